// Round 1
// baseline (832.525 us; speedup 1.0000x reference)
//
#include <hip/hip_runtime.h>
#include <math.h>

// Tables replicating the Python _SRC/_ROT grid mapping (H=32).
// src[p] == 255 means masked (full row is 0 there); otherwise src in [0, L).
struct Tables {
    unsigned char src[1024];
    unsigned char rot[1024];
};

// out[b,t,c] = x[b,t,c] + full[t,c]
//   full[0, g*128+c]   = cls[c]
//   full[1+p, g*128+c] = src[p]==255 ? 0 : pe[(src[p]*8 + ((g - rot[p]) & 7)) * 128 + c]
__global__ __launch_bounds__(256) void pe_add_kernel(
    const float* __restrict__ x,
    const float* __restrict__ pe,
    const float* __restrict__ cls,
    float* __restrict__ out,
    const Tables tbl)
{
    const int t   = blockIdx.x;      // token index 0..1024
    const int b   = blockIdx.y;      // batch index
    const int tid = threadIdx.x;     // 0..255
    const int ch  = tid << 2;        // channel 0..1023, float4 per thread

    const size_t off = ((size_t)b * 1025 + (size_t)t) * 1024 + (size_t)ch;
    const float4 xv = *reinterpret_cast<const float4*>(x + off);

    float4 fv = make_float4(0.f, 0.f, 0.f, 0.f);
    if (t == 0) {
        // cls row: cls_pos_eighth tiled 8x along channels
        fv = *reinterpret_cast<const float4*>(cls + (ch & 127));
    } else {
        const int p = t - 1;
        const int s = (int)tbl.src[p];          // wave-uniform scalar load
        if (s != 255) {
            const int g   = ch >> 7;            // which eighth, 0..7
            const int grp = (g + 8 - (int)tbl.rot[p]) & 7;
            fv = *reinterpret_cast<const float4*>(
                pe + (size_t)(s * 8 + grp) * 128 + (size_t)(ch & 127));
        }
    }

    float4 ov;
    ov.x = xv.x + fv.x;
    ov.y = xv.y + fv.y;
    ov.z = xv.z + fv.z;
    ov.w = xv.w + fv.w;
    *reinterpret_cast<float4*>(out + off) = ov;
}

// Host-side table construction. Must bit-match the Python reference:
// CPython's math.atan2/cos/sin call this same libm; Python round() is
// nearest-ties-to-even, which is lrint() under the default FP env.
static void build_tables(Tables* tbl)
{
    const int h = 32;
    const double center = (h - 1) / 2.0;   // 15.5
    const double thr = M_PI / 4.0 + 1e-06;

    int src[1024];
    int rot[1024];
    for (int p = 0; p < 1024; ++p) { src[p] = -1; rot[p] = 0; }

    // _learnable_positions: row-major scan, keep angle in [0, pi/4 + 1e-6]
    int pos_i[1024], pos_j[1024];
    int L = 0;
    for (int i = 0; i < h; ++i) {
        for (int j = 0; j < h; ++j) {
            const double y = center - (double)i;
            const double x = (double)j - center;
            if (x == 0.0 && y == 0.0) {
                pos_i[L] = i; pos_j[L] = j; ++L;
                continue;
            }
            double ang = atan2(y, x);
            if (ang < 0.0) ang += 2.0 * M_PI;
            if (ang >= 0.0 && ang <= thr) {
                pos_i[L] = i; pos_j[L] = j; ++L;
            }
        }
    }

    // _grid_mapping: iterate positions in order, k in 0..7, later writes win
    for (int idx = 0; idx < L; ++idx) {
        const double y = center - (double)pos_i[idx];
        const double x = (double)pos_j[idx] - center;
        for (int k = 0; k < 8; ++k) {
            const double theta = ((double)k * M_PI) / 4.0;  // k * math.pi / 4
            const double ct = cos(theta), st = sin(theta);
            const double xn = ct * x - st * y;
            const double yn = st * x + ct * y;
            long ir = lrint(center - yn);   // Python round(): ties to even
            long jr = lrint(center + xn);
            if (ir < 0) ir = 0; if (ir > h - 1) ir = h - 1;
            if (jr < 0) jr = 0; if (jr > h - 1) jr = h - 1;
            const int p = (int)(ir * h + jr);
            src[p] = idx;
            rot[p] = k;
        }
    }

    for (int p = 0; p < 1024; ++p) {
        tbl->src[p] = (src[p] < 0) ? (unsigned char)255 : (unsigned char)src[p];
        tbl->rot[p] = (unsigned char)rot[p];
    }
}

extern "C" void kernel_launch(void* const* d_in, const int* in_sizes, int n_in,
                              void* d_out, int out_size, void* d_ws, size_t ws_size,
                              hipStream_t stream)
{
    const float* x   = (const float*)d_in[0];  // (B, 1025, 1024) f32
    const float* pe  = (const float*)d_in[1];  // (1, L, 1024) f32
    const float* cls = (const float*)d_in[2];  // (1, 1, 128) f32
    float* out = (float*)d_out;

    const int tokens = 1 + 32 * 32;            // 1025
    const int chans  = 8 * 128;                // 1024
    const int B = in_sizes[0] / (tokens * chans);

    // Deterministic; recomputed identically on every call (graph-capture safe:
    // table is baked into the kernarg at capture time).
    Tables tbl;
    build_tables(&tbl);

    dim3 grid(tokens, B);
    dim3 block(256);
    pe_add_kernel<<<grid, block, 0, stream>>>(x, pe, cls, out, tbl);
}